// Round 2
// baseline (179.403 us; speedup 1.0000x reference)
//
#include <hip/hip_runtime.h>

#define KS 3
#define K3 27
#define CIN 8
#define COUT 64
#define CC_EPS 1e-12f

// One wave (64 lanes) per output point.
// lane = jsub*8 + c : jsub = 8-way split over input points, c = input channel.
// Each lane keeps acc[27] (per-bin accumulation for its channel) in registers
// with static indexing only; butterfly-reduce over jsub at the end; then the
// 64 lanes switch roles: lane = output channel f for the 216-dot epilogue.
//
// Bin mapping (matches reference _OFFSETS=[dz,dy,dx] + _STRIDES=[9,3,1]):
// rel component 0 -> stride 9, component 1 -> stride 3, component 2 -> stride 1.
__global__ __launch_bounds__(256)
void cconv_fused_kernel(const float* __restrict__ features,
                        const float* __restrict__ pos_input,
                        const float* __restrict__ pos_output,
                        const float* __restrict__ extents,
                        const float* __restrict__ kern,
                        const float* __restrict__ bias,
                        float* __restrict__ out,
                        int Ni, int No)
{
    const int tid  = threadIdx.x;
    const int wave = tid >> 6;        // 0..3 (4 waves per block)
    const int lane = tid & 63;
    const int jsub = lane >> 3;       // 0..7
    const int i    = blockIdx.x * 4 + wave;   // output point

    __shared__ float Bsh[4][K3][CIN];

    const bool active = (i < No);

    float acc[K3];
#pragma unroll
    for (int k = 0; k < K3; ++k) acc[k] = 0.0f;

    if (active) {
        const float s  = 2.0f / extents[0];
        const float ox = pos_output[i * 3 + 0];
        const float oy = pos_output[i * 3 + 1];
        const float oz = pos_output[i * 3 + 2];

#pragma unroll 2
        for (int j0 = 0; j0 < Ni; j0 += 8) {
            const int j = j0 + jsub;
            const bool valid = (j < Ni);
            float rx = 0.f, ry = 0.f, rz = 0.f, fval = 0.f;
            if (valid) {
                rx   = (pos_input[j * 3 + 0] - ox) * s;   // component 0 -> stride 9
                ry   = (pos_input[j * 3 + 1] - oy) * s;   // component 1 -> stride 3
                rz   = (pos_input[j * 3 + 2] - oz) * s;   // component 2 -> stride 1
                fval = features[j0 * CIN + lane];   // == features[j*CIN + c], coalesced
            }
            const float r2 = rx * rx + ry * ry + rz * rz;
            if (valid && r2 < 1.0f) {
                const float u   = 1.0f - r2;
                const float win = u * u * u;                       // poly6 window
                const float r   = sqrtf(fmaxf(r2, CC_EPS));
                const float linf = fmaxf(fmaxf(fabsf(rx), fabsf(ry)), fabsf(rz));
                const float scale = (linf > CC_EPS) ? (r / linf) : 1.0f;
                // q = clip(rel*scale,-1,1); t = (q+1)*0.5*(KS-1) = q+1 in [0,2]
                const float ta = fminf(fmaxf(rx * scale, -1.f), 1.f) + 1.0f;
                const float tb = fminf(fmaxf(ry * scale, -1.f), 1.f) + 1.0f;
                const float tc = fminf(fmaxf(rz * scale, -1.f), 1.f) + 1.0f;
                // separable 1-D trilinear weights over the 3 bins of each axis:
                // t in [0,1): {1-t, t, 0} ; t in [1,2]: {0, 2-t, t-1}
                const float wa0 = fmaxf(1.0f - ta, 0.0f), wa2 = fmaxf(ta - 1.0f, 0.0f);
                const float wb0 = fmaxf(1.0f - tb, 0.0f), wb2 = fmaxf(tb - 1.0f, 0.0f);
                const float wc0 = fmaxf(1.0f - tc, 0.0f), wc2 = fmaxf(tc - 1.0f, 0.0f);
                const float wa1 = 1.0f - wa0 - wa2;
                const float wb1 = 1.0f - wb0 - wb2;
                const float wc1 = 1.0f - wc0 - wc2;

                const float wav[3] = { wa0 * win,  wa1 * win,  wa2 * win  };  // stride 9
                const float wbv[3] = { wb0,        wb1,        wb2        };  // stride 3
                const float wcf[3] = { wc0 * fval, wc1 * fval, wc2 * fval };  // stride 1
#pragma unroll
                for (int a = 0; a < 3; ++a) {
#pragma unroll
                    for (int b = 0; b < 3; ++b) {
                        const float wab = wav[a] * wbv[b];
#pragma unroll
                        for (int c = 0; c < 3; ++c) {
                            acc[a * 9 + b * 3 + c] =
                                fmaf(wab, wcf[c], acc[a * 9 + b * 3 + c]);
                        }
                    }
                }
            }
        }

        // reduce over the 8 jsub slices (lanes differing in bits 3..5)
#pragma unroll
        for (int k = 0; k < K3; ++k) {
            float v = acc[k];
            v += __shfl_xor(v, 8, 64);
            v += __shfl_xor(v, 16, 64);
            v += __shfl_xor(v, 32, 64);
            acc[k] = v;
        }

        if (jsub == 0) {
            const int c = lane & 7;
#pragma unroll
            for (int k = 0; k < K3; ++k) Bsh[wave][k][c] = acc[k];
        }
    }

    __syncthreads();

    if (active) {
        // lane -> output channel f; 216-long dot with L2-resident kernel weights
        const int f = lane;
        float o = bias[f];
#pragma unroll 3
        for (int k = 0; k < K3; ++k) {
#pragma unroll
            for (int cc = 0; cc < CIN; ++cc) {
                o = fmaf(Bsh[wave][k][cc], kern[(k * CIN + cc) * COUT + f], o);
            }
        }
        out[i * COUT + f] = fmaxf(o, 0.0f);   // relu
    }
}

extern "C" void kernel_launch(void* const* d_in, const int* in_sizes, int n_in,
                              void* d_out, int out_size, void* d_ws, size_t ws_size,
                              hipStream_t stream) {
    const float* features   = (const float*)d_in[0];
    const float* pos_input  = (const float*)d_in[1];
    const float* pos_output = (const float*)d_in[2];
    const float* extents    = (const float*)d_in[3];
    const float* kern       = (const float*)d_in[4];
    const float* bias       = (const float*)d_in[5];
    float* out = (float*)d_out;

    const int Ni = in_sizes[0] / CIN;
    const int No = in_sizes[2] / 3;

    dim3 block(256);
    dim3 grid((No + 3) / 4);
    cconv_fused_kernel<<<grid, block, 0, stream>>>(features, pos_input, pos_output,
                                                   extents, kern, bias, out, Ni, No);
}

// Round 6
// 117.924 us; speedup vs baseline: 1.5214x; 1.5214x over previous
//
#include <hip/hip_runtime.h>

#define KS 3
#define K3 27
#define CIN 8
#define COUT 64
#define CC_EPS 1e-12f
#define LIST_CAP 1024   // per-wave neighbor list capacity = ceil(Ni/2), Ni<=2048

// Block = 256 threads = 4 waves = 2 output points x 2 j-range halves.
// Phase 1: lane=j compaction of inside pairs (r2<1) into LDS ushort list.
// Phase 2: lane=(jsub,c) dense interp over compacted list only.
// Epilogue: 216-dot GEMM split across the 4 waves by k-range.
__global__ __launch_bounds__(256)
void cconv_fused_kernel(const float* __restrict__ features,
                        const float* __restrict__ pos_input,
                        const float* __restrict__ pos_output,
                        const float* __restrict__ extents,
                        const float* __restrict__ kern,
                        const float* __restrict__ bias,
                        float* __restrict__ out,
                        int Ni, int No)
{
    const int tid  = threadIdx.x;
    const int wave = tid >> 6;        // 0..3
    const int lane = tid & 63;
    const int p    = wave >> 1;       // point slot in block (0..1)
    const int half = wave & 1;        // j-range half
    const int i    = blockIdx.x * 2 + p;

    __shared__ unsigned short idx[4][LIST_CAP];
    __shared__ float Bsh[4][K3][CIN];
    __shared__ float part[4][COUT];

    const bool activeI = (i < No);

    float ox = 0.f, oy = 0.f, oz = 0.f, s = 1.f;
    if (activeI) {
        s  = 2.0f / extents[0];
        ox = pos_output[i * 3 + 0];
        oy = pos_output[i * 3 + 1];
        oz = pos_output[i * 3 + 2];
    }

    // ---------------- Phase 1: compact inside-ball neighbor indices ----------
    const int jbeg = half ? (Ni >> 1) : 0;
    const int jend = half ? Ni : (Ni >> 1);
    int cnt = 0;
    if (activeI) {
        for (int j0 = jbeg; j0 < jend; j0 += 64) {
            const int j = j0 + lane;
            bool inside = false;
            if (j < jend) {
                const float rx = (pos_input[j * 3 + 0] - ox) * s;
                const float ry = (pos_input[j * 3 + 1] - oy) * s;
                const float rz = (pos_input[j * 3 + 2] - oz) * s;
                inside = (rx * rx + ry * ry + rz * rz) < 1.0f;
            }
            const unsigned long long m = __ballot(inside);
            if (inside) {
                const int pre = __popcll(m & ((1ull << lane) - 1ull));
                idx[wave][cnt + pre] = (unsigned short)j;
            }
            cnt += (int)__popcll(m);
        }
    }

    // ---------------- Phase 2: dense interp over compacted list --------------
    float acc[K3];
#pragma unroll
    for (int k = 0; k < K3; ++k) acc[k] = 0.0f;

    if (activeI && cnt > 0) {
        const int jsub = lane >> 3;
        const int c    = lane & 7;
        for (int it = 0; it < cnt; it += 8) {
            const int  slot  = it + jsub;
            const bool valid = (slot < cnt);
            const int  j     = idx[wave][valid ? slot : (cnt - 1)];

            const float rx = (pos_input[j * 3 + 0] - ox) * s;   // comp0 -> stride 9
            const float ry = (pos_input[j * 3 + 1] - oy) * s;   // comp1 -> stride 3
            const float rz = (pos_input[j * 3 + 2] - oz) * s;   // comp2 -> stride 1
            const float fval = valid ? features[j * CIN + c] : 0.0f;

            const float r2  = rx * rx + ry * ry + rz * rz;      // < 1 guaranteed
            const float u   = 1.0f - r2;
            const float win = u * u * u;                        // poly6 window
            const float r   = sqrtf(fmaxf(r2, CC_EPS));
            const float linf = fmaxf(fmaxf(fabsf(rx), fabsf(ry)), fabsf(rz));
            const float scale = (linf > CC_EPS) ? (r / linf) : 1.0f;
            const float ta = fminf(fmaxf(rx * scale, -1.f), 1.f) + 1.0f;
            const float tb = fminf(fmaxf(ry * scale, -1.f), 1.f) + 1.0f;
            const float tc = fminf(fmaxf(rz * scale, -1.f), 1.f) + 1.0f;
            // 1-D trilinear over 3 bins: t<1:{1-t,t,0}, t>=1:{0,2-t,t-1}
            const float wa0 = fmaxf(1.0f - ta, 0.0f), wa2 = fmaxf(ta - 1.0f, 0.0f);
            const float wb0 = fmaxf(1.0f - tb, 0.0f), wb2 = fmaxf(tb - 1.0f, 0.0f);
            const float wc0 = fmaxf(1.0f - tc, 0.0f), wc2 = fmaxf(tc - 1.0f, 0.0f);
            const float wa1 = 1.0f - wa0 - wa2;
            const float wb1 = 1.0f - wb0 - wb2;
            const float wc1 = 1.0f - wc0 - wc2;

            const float wav[3] = { wa0 * win,  wa1 * win,  wa2 * win  };
            const float wbv[3] = { wb0,        wb1,        wb2        };
            const float wcf[3] = { wc0 * fval, wc1 * fval, wc2 * fval };
#pragma unroll
            for (int a = 0; a < 3; ++a) {
#pragma unroll
                for (int b = 0; b < 3; ++b) {
                    const float wab = wav[a] * wbv[b];
#pragma unroll
                    for (int c3 = 0; c3 < 3; ++c3) {
                        acc[a * 9 + b * 3 + c3] =
                            fmaf(wab, wcf[c3], acc[a * 9 + b * 3 + c3]);
                    }
                }
            }
        }
    }

    // reduce over jsub (lanes differing in bits 3..5), write wave's B slice
#pragma unroll
    for (int k = 0; k < K3; ++k) {
        float v = acc[k];
        v += __shfl_xor(v, 8, 64);
        v += __shfl_xor(v, 16, 64);
        v += __shfl_xor(v, 32, 64);
        acc[k] = v;
    }
    if ((lane >> 3) == 0) {
        const int c = lane & 7;
#pragma unroll
        for (int k = 0; k < K3; ++k) Bsh[wave][k][c] = acc[k];
    }

    __syncthreads();

    // ---------------- Epilogue: out = relu(B . kernel + bias) ----------------
    {
        const int kb = half ? 14 : 0;
        const int ke = half ? K3 : 14;
        const int f  = lane;
        float o = 0.0f;
        for (int k = kb; k < ke; ++k) {
#pragma unroll
            for (int cc = 0; cc < CIN; ++cc) {
                const float b = Bsh[2 * p][k][cc] + Bsh[2 * p + 1][k][cc];
                o = fmaf(b, kern[(k * CIN + cc) * COUT + f], o);
            }
        }
        part[wave][f] = o;
    }
    __syncthreads();

    if (tid < 128) {
        const int pp = tid >> 6;
        const int f  = tid & 63;
        const int ii = blockIdx.x * 2 + pp;
        if (ii < No) {
            const float o = bias[f] + part[2 * pp][f] + part[2 * pp + 1][f];
            out[ii * COUT + f] = fmaxf(o, 0.0f);
        }
    }
}

extern "C" void kernel_launch(void* const* d_in, const int* in_sizes, int n_in,
                              void* d_out, int out_size, void* d_ws, size_t ws_size,
                              hipStream_t stream) {
    const float* features   = (const float*)d_in[0];
    const float* pos_input  = (const float*)d_in[1];
    const float* pos_output = (const float*)d_in[2];
    const float* extents    = (const float*)d_in[3];
    const float* kern       = (const float*)d_in[4];
    const float* bias       = (const float*)d_in[5];
    float* out = (float*)d_out;

    const int Ni = in_sizes[0] / CIN;   // 2048 (LIST_CAP assumes Ni <= 2048)
    const int No = in_sizes[2] / 3;

    dim3 block(256);
    dim3 grid((No + 1) / 2);
    cconv_fused_kernel<<<grid, block, 0, stream>>>(features, pos_input, pos_output,
                                                   extents, kern, bias, out, Ni, No);
}

// Round 8
// 98.724 us; speedup vs baseline: 1.8172x; 1.1945x over previous
//
#include <hip/hip_runtime.h>

#define K3 27
#define CIN 8
#define COUT 64
#define CC_EPS 1e-12f
#define NI_CAP 2048   // shared list capacity (Ni <= 2048 in this problem)

// Block = 256 threads = 4 waves = ONE output point.
// Phase 1: all 4 waves ballot-compact inside-ball j's into ONE shared list
//          (LDS atomic base) -> exact intra-block balance in phase 2.
// Phase 2: waves consume interleaved 8-slot chunks of the compacted list;
//          lane=(jsub,c): 8 slots/iter, each 8-lane group shares one j.
// Epilogue: cross-wave sum B, then 4-way k-split GEMM, relu, store.
__global__ __launch_bounds__(256)
void cconv_fused_kernel(const float* __restrict__ features,
                        const float* __restrict__ pos_input,
                        const float* __restrict__ pos_output,
                        const float* __restrict__ extents,
                        const float* __restrict__ kern,
                        const float* __restrict__ bias,
                        float* __restrict__ out,
                        int Ni, int No)
{
    const int tid  = threadIdx.x;
    const int w    = tid >> 6;        // wave 0..3
    const int lane = tid & 63;
    const int i    = blockIdx.x;      // output point

    __shared__ unsigned short idx[NI_CAP];
    __shared__ int   cnt_sh;
    __shared__ float Bsh[4][K3][CIN];
    __shared__ float Bf[K3][CIN];
    __shared__ float part[4][COUT];

    if (tid == 0) cnt_sh = 0;
    __syncthreads();

    const float s  = 2.0f / extents[0];
    const float ox = pos_output[i * 3 + 0];
    const float oy = pos_output[i * 3 + 1];
    const float oz = pos_output[i * 3 + 2];

    // ---------------- Phase 1: cooperative ballot compaction ----------------
    for (int j0 = w * 64; j0 < Ni; j0 += 256) {
        const int j = j0 + lane;
        bool inside = false;
        if (j < Ni) {
            const float rx = (pos_input[j * 3 + 0] - ox) * s;
            const float ry = (pos_input[j * 3 + 1] - oy) * s;
            const float rz = (pos_input[j * 3 + 2] - oz) * s;
            inside = (rx * rx + ry * ry + rz * rz) < 1.0f;
        }
        const unsigned long long m = __ballot(inside);
        const int nin = (int)__popcll(m);
        int base = 0;
        if (lane == 0 && nin) base = atomicAdd(&cnt_sh, nin);
        base = __shfl(base, 0, 64);
        if (inside) {
            const int pre = __popcll(m & ((1ull << lane) - 1ull));
            idx[base + pre] = (unsigned short)j;
        }
    }
    __syncthreads();
    const int total = cnt_sh;

    // ---------------- Phase 2: balanced interp over shared list -------------
    float acc[K3];
#pragma unroll
    for (int k = 0; k < K3; ++k) acc[k] = 0.0f;

    const int jsub = lane >> 3;
    const int c    = lane & 7;
    for (int base = w * 8; base < total; base += 32) {
        const int  slot  = base + jsub;
        const bool valid = (slot < total);
        const int  j     = idx[valid ? slot : total - 1];

        const float rx = (pos_input[j * 3 + 0] - ox) * s;   // comp0 -> stride 9
        const float ry = (pos_input[j * 3 + 1] - oy) * s;   // comp1 -> stride 3
        const float rz = (pos_input[j * 3 + 2] - oz) * s;   // comp2 -> stride 1
        const float fval = valid ? features[j * CIN + c] : 0.0f;

        const float r2  = rx * rx + ry * ry + rz * rz;      // < 1 guaranteed
        const float u   = 1.0f - r2;
        const float win = u * u * u;                        // poly6 window
        // fast HW approx (v_sqrt_f32 / v_rcp_f32, ~1 ulp; threshold 5.6e-2)
        const float r    = __builtin_amdgcn_sqrtf(fmaxf(r2, CC_EPS));
        const float linf = fmaxf(fmaxf(fabsf(rx), fabsf(ry)), fabsf(rz));
        const float scale = (linf > CC_EPS) ? r * __builtin_amdgcn_rcpf(linf) : 1.0f;
        const float ta = fminf(fmaxf(rx * scale, -1.f), 1.f) + 1.0f;
        const float tb = fminf(fmaxf(ry * scale, -1.f), 1.f) + 1.0f;
        const float tc = fminf(fmaxf(rz * scale, -1.f), 1.f) + 1.0f;
        // 1-D trilinear over 3 bins: t<1:{1-t,t,0}, t>=1:{0,2-t,t-1}
        const float wa0 = fmaxf(1.0f - ta, 0.0f), wa2 = fmaxf(ta - 1.0f, 0.0f);
        const float wb0 = fmaxf(1.0f - tb, 0.0f), wb2 = fmaxf(tb - 1.0f, 0.0f);
        const float wc0 = fmaxf(1.0f - tc, 0.0f), wc2 = fmaxf(tc - 1.0f, 0.0f);
        const float wa1 = 1.0f - wa0 - wa2;
        const float wb1 = 1.0f - wb0 - wb2;
        const float wc1 = 1.0f - wc0 - wc2;

        const float wav[3] = { wa0 * win,  wa1 * win,  wa2 * win  };
        const float wbv[3] = { wb0,        wb1,        wb2        };
        const float wcf[3] = { wc0 * fval, wc1 * fval, wc2 * fval };
#pragma unroll
        for (int a = 0; a < 3; ++a) {
#pragma unroll
            for (int b = 0; b < 3; ++b) {
                const float wab = wav[a] * wbv[b];
#pragma unroll
                for (int c3 = 0; c3 < 3; ++c3) {
                    acc[a * 9 + b * 3 + c3] =
                        fmaf(wab, wcf[c3], acc[a * 9 + b * 3 + c3]);
                }
            }
        }
    }

    // within-wave reduce over jsub (lanes differing in bits 3..5)
#pragma unroll
    for (int k = 0; k < K3; ++k) {
        float v = acc[k];
        v += __shfl_xor(v, 8, 64);
        v += __shfl_xor(v, 16, 64);
        v += __shfl_xor(v, 32, 64);
        acc[k] = v;
    }
    if (jsub == 0) {
#pragma unroll
        for (int k = 0; k < K3; ++k) Bsh[w][k][c] = acc[k];
    }
    __syncthreads();

    // cross-wave sum: Bf[k][c] = sum_w Bsh[w][k][c]
    if (tid < K3 * CIN) {
        const int k  = tid >> 3;
        const int cc = tid & 7;
        Bf[k][cc] = Bsh[0][k][cc] + Bsh[1][k][cc] + Bsh[2][k][cc] + Bsh[3][k][cc];
    }
    __syncthreads();

    // ---------------- Epilogue: out = relu(Bf . kernel + bias), 4-way k-split
    {
        const int kb = w * 7;
        const int ke = (kb + 7 < K3) ? kb + 7 : K3;
        const int f  = lane;
        float o = 0.0f;
        for (int k = kb; k < ke; ++k) {
#pragma unroll
            for (int cc = 0; cc < CIN; ++cc) {
                o = fmaf(Bf[k][cc], kern[(k * CIN + cc) * COUT + f], o);
            }
        }
        part[w][f] = o;
    }
    __syncthreads();

    if (tid < COUT) {
        const float o = bias[tid] + part[0][tid] + part[1][tid]
                                  + part[2][tid] + part[3][tid];
        out[i * COUT + tid] = fmaxf(o, 0.0f);
    }
}

extern "C" void kernel_launch(void* const* d_in, const int* in_sizes, int n_in,
                              void* d_out, int out_size, void* d_ws, size_t ws_size,
                              hipStream_t stream) {
    const float* features   = (const float*)d_in[0];
    const float* pos_input  = (const float*)d_in[1];
    const float* pos_output = (const float*)d_in[2];
    const float* extents    = (const float*)d_in[3];
    const float* kern       = (const float*)d_in[4];
    const float* bias       = (const float*)d_in[5];
    float* out = (float*)d_out;

    const int Ni = in_sizes[0] / CIN;   // 2048 (NI_CAP assumes Ni <= 2048)
    const int No = in_sizes[2] / 3;

    dim3 block(256);
    dim3 grid(No);
    cconv_fused_kernel<<<grid, block, 0, stream>>>(features, pos_input, pos_output,
                                                   extents, kern, bias, out, Ni, No);
}

// Round 10
// 95.197 us; speedup vs baseline: 1.8845x; 1.0371x over previous
//
#include <hip/hip_runtime.h>

#define K3 27
#define CIN 8
#define COUT 64
#define CC_EPS 1e-12f
#define CHUNK 32
#define RECW 12   // weight record: wab[9] (win-premultiplied a*b) + wcv[3]

// Block = 256 threads = 4 waves = ONE output point.
// Phase 1: cooperative ballot-compaction of inside-ball j's into shared idx[].
// Phase 2 per wave, chunks of 32 slots (stride 128):
//   stage A: lane(<32) computes ONE slot's geometry -> 12-float LDS record.
//   stage B: 8-lane group g, round t consumes record l=t*8+g (conflict-free
//            b128 broadcast reads), 3 mult + 27 FMA per channel-lane.
// Epilogue: shfl-reduce over groups, cross-wave sum into Bsh[0], 4-way k-split
// GEMM, relu, store. part[] aliases idx[] to keep LDS at ~13.7 KB.
__global__ __launch_bounds__(256, 8)
void cconv_fused_kernel(const float* __restrict__ features,
                        const float* __restrict__ pos_input,
                        const float* __restrict__ pos_output,
                        const float* __restrict__ extents,
                        const float* __restrict__ kern,
                        const float* __restrict__ bias,
                        float* __restrict__ out,
                        int Ni, int No)
{
    const int tid  = threadIdx.x;
    const int w    = tid >> 6;        // wave 0..3
    const int lane = tid & 63;
    const int g    = lane >> 3;       // 8-lane group 0..7
    const int c    = lane & 7;        // input channel
    const int i    = blockIdx.x;      // output point

    // carved LDS: idx[2048] ushort (aliased by part[4][COUT] in epilogue),
    // wrec[4][CHUNK][RECW] f32, Bsh[4][K3][CIN] f32
    __shared__ __align__(16) char smem[4096 + 4*CHUNK*RECW*4 + 4*K3*CIN*4];
    unsigned short* idx  = (unsigned short*)smem;
    float*          part = (float*)smem;                            // aliases idx
    float*          wrec = (float*)(smem + 4096);
    float*          Bsh  = (float*)(smem + 4096 + 4*CHUNK*RECW*4);
    __shared__ int cnt_sh;

    if (tid == 0) cnt_sh = 0;
    __syncthreads();

    const float s  = 2.0f / extents[0];
    const float ox = pos_output[i*3+0];
    const float oy = pos_output[i*3+1];
    const float oz = pos_output[i*3+2];

    // ---------------- Phase 1: cooperative ballot compaction ----------------
    for (int j0 = w*64; j0 < Ni; j0 += 256) {
        const int j = j0 + lane;
        bool inside = false;
        if (j < Ni) {
            const float rx = (pos_input[j*3+0]-ox)*s;
            const float ry = (pos_input[j*3+1]-oy)*s;
            const float rz = (pos_input[j*3+2]-oz)*s;
            inside = (rx*rx + ry*ry + rz*rz) < 1.0f;
        }
        const unsigned long long m = __ballot(inside);
        const int nin = (int)__popcll(m);
        int base = 0;
        if (lane == 0 && nin) base = atomicAdd(&cnt_sh, nin);
        base = __shfl(base, 0, 64);
        if (inside) {
            const int pre = __popcll(m & ((1ull<<lane)-1ull));
            idx[base+pre] = (unsigned short)j;
        }
    }
    __syncthreads();
    const int total = cnt_sh;

    // ---------------- Phase 2: stage-A/stage-B dedup over compacted list ----
    float acc[K3];
#pragma unroll
    for (int k = 0; k < K3; ++k) acc[k] = 0.0f;

    for (int cb = w*CHUNK; cb < total; cb += 4*CHUNK) {
        // ---- stage A: one lane per slot, geometry -> 12-float record
        if (lane < CHUNK) {
            const int  slot = cb + lane;
            const bool va   = slot < total;
            const int  j    = idx[va ? slot : 0];
            float ab0=0,ab1=0,ab2=0,ab3=0,ab4=0,ab5=0,ab6=0,ab7=0,ab8=0;
            float wc0=0,wc1=0,wc2=0;
            if (va) {
                const float rx = (pos_input[j*3+0]-ox)*s;   // comp0 -> stride 9
                const float ry = (pos_input[j*3+1]-oy)*s;   // comp1 -> stride 3
                const float rz = (pos_input[j*3+2]-oz)*s;   // comp2 -> stride 1
                const float r2  = rx*rx + ry*ry + rz*rz;    // < 1 guaranteed
                const float u   = 1.0f - r2;
                const float win = u*u*u;                    // poly6 window
                const float r    = __builtin_amdgcn_sqrtf(fmaxf(r2, CC_EPS));
                const float linf = fmaxf(fmaxf(fabsf(rx), fabsf(ry)), fabsf(rz));
                const float scale = (linf > CC_EPS) ? r*__builtin_amdgcn_rcpf(linf) : 1.0f;
                const float ta = fminf(fmaxf(rx*scale, -1.f), 1.f) + 1.0f;
                const float tb = fminf(fmaxf(ry*scale, -1.f), 1.f) + 1.0f;
                const float tc = fminf(fmaxf(rz*scale, -1.f), 1.f) + 1.0f;
                // 1-D trilinear over 3 bins: t<1:{1-t,t,0}, t>=1:{0,2-t,t-1}
                const float wa0 = fmaxf(1.0f-ta, 0.0f), wa2 = fmaxf(ta-1.0f, 0.0f);
                const float wb0 = fmaxf(1.0f-tb, 0.0f), wb2 = fmaxf(tb-1.0f, 0.0f);
                wc0 = fmaxf(1.0f-tc, 0.0f); wc2 = fmaxf(tc-1.0f, 0.0f);
                const float wa1 = 1.0f - wa0 - wa2;
                const float wb1 = 1.0f - wb0 - wb2;
                wc1 = 1.0f - wc0 - wc2;
                const float a0 = wa0*win, a1 = wa1*win, a2 = wa2*win;
                ab0 = a0*wb0; ab1 = a0*wb1; ab2 = a0*wb2;
                ab3 = a1*wb0; ab4 = a1*wb1; ab5 = a1*wb2;
                ab6 = a2*wb0; ab7 = a2*wb1; ab8 = a2*wb2;
            }
            float* rec = wrec + (w*CHUNK + lane)*RECW;
            ((float4*)rec)[0] = make_float4(ab0, ab1, ab2, ab3);
            ((float4*)rec)[1] = make_float4(ab4, ab5, ab6, ab7);
            ((float4*)rec)[2] = make_float4(ab8, wc0, wc1, wc2);
        }
        // same-wave ds_write -> ds_read: DS pipe is in-order per wave; wait for
        // register returns + pin scheduling as insurance.
        asm volatile("s_waitcnt lgkmcnt(0)" ::: "memory");
        __builtin_amdgcn_sched_barrier(0);

        // ---- stage B: group g, round t consumes record l = t*8+g
#pragma unroll
        for (int t = 0; t < CHUNK/8; ++t) {
            const int l    = t*8 + g;
            const int slot = cb + l;
            const float* rec = wrec + (w*CHUNK + l)*RECW;
            const float4 r0 = ((const float4*)rec)[0];
            const float4 r1 = ((const float4*)rec)[1];
            const float4 r2 = ((const float4*)rec)[2];
            const int   jj = idx[slot < total ? slot : 0];
            const float fv = features[jj*CIN + c];          // zero-weight if invalid
            const float wabv[9] = { r0.x, r0.y, r0.z, r0.w,
                                    r1.x, r1.y, r1.z, r1.w, r2.x };
            const float fcs[3]  = { r2.y*fv, r2.z*fv, r2.w*fv };
#pragma unroll
            for (int ab = 0; ab < 9; ++ab) {
#pragma unroll
                for (int cc = 0; cc < 3; ++cc) {
                    acc[ab*3 + cc] = fmaf(wabv[ab], fcs[cc], acc[ab*3 + cc]);
                }
            }
        }
    }

    // within-wave reduce over groups (lane bits 3..5)
#pragma unroll
    for (int k = 0; k < K3; ++k) {
        float v = acc[k];
        v += __shfl_xor(v, 8, 64);
        v += __shfl_xor(v, 16, 64);
        v += __shfl_xor(v, 32, 64);
        acc[k] = v;
    }
    if (g == 0) {
#pragma unroll
        for (int k = 0; k < K3; ++k) Bsh[(w*K3 + k)*CIN + c] = acc[k];
    }
    __syncthreads();

    // cross-wave sum into Bsh[0]
    if (tid < K3*CIN) {
        const int k  = tid >> 3;
        const int cc = tid & 7;
        Bsh[k*CIN + cc] = Bsh[k*CIN + cc]
                        + Bsh[(K3   + k)*CIN + cc]
                        + Bsh[(2*K3 + k)*CIN + cc]
                        + Bsh[(3*K3 + k)*CIN + cc];
    }
    __syncthreads();

    // ---------------- Epilogue: out = relu(B . kernel + bias), 4-way k-split
    {
        const int kb = w*7;
        const int ke = (kb + 7 < K3) ? kb + 7 : K3;
        float o = 0.0f;
        for (int k = kb; k < ke; ++k) {
#pragma unroll
            for (int cc = 0; cc < CIN; ++cc) {
                o = fmaf(Bsh[k*CIN + cc], kern[(k*CIN + cc)*COUT + lane], o);
            }
        }
        part[w*COUT + lane] = o;    // part aliases idx (idx dead after phase 2)
    }
    __syncthreads();

    if (tid < COUT) {
        const float o = bias[tid] + part[tid] + part[COUT + tid]
                      + part[2*COUT + tid] + part[3*COUT + tid];
        out[i*COUT + tid] = fmaxf(o, 0.0f);
    }
}

extern "C" void kernel_launch(void* const* d_in, const int* in_sizes, int n_in,
                              void* d_out, int out_size, void* d_ws, size_t ws_size,
                              hipStream_t stream) {
    const float* features   = (const float*)d_in[0];
    const float* pos_input  = (const float*)d_in[1];
    const float* pos_output = (const float*)d_in[2];
    const float* extents    = (const float*)d_in[3];
    const float* kern       = (const float*)d_in[4];
    const float* bias       = (const float*)d_in[5];
    float* out = (float*)d_out;

    const int Ni = in_sizes[0] / CIN;   // 2048 (idx cap assumes Ni <= 2048)
    const int No = in_sizes[2] / 3;

    dim3 block(256);
    dim3 grid(No);
    cconv_fused_kernel<<<grid, block, 0, stream>>>(features, pos_input, pos_output,
                                                   extents, kern, bias, out, Ni, No);
}